// Round 1
// baseline (418.307 us; speedup 1.0000x reference)
//
#include <hip/hip_runtime.h>
#include <math.h>

// GAT 2-layer forward. N=50000 nodes, E=800000 edges, D=128, H=4 heads, F=32.
// edge_index arrives as int32 (JAX default x64-disabled demotes int64->int32).
constexpr int NN = 50000;
constexpr int NE = 800000;
constexpr int D  = 128;
constexpr int NH = 4;

// ---------------- CSR build (once per call; shared by both layers) ----------
__global__ void hist_kernel(const int* __restrict__ dst, int* __restrict__ cnt) {
    int e = blockIdx.x * blockDim.x + threadIdx.x;
    if (e < NE) atomicAdd(&cnt[dst[e]], 1);
}

__global__ __launch_bounds__(1024) void scan_kernel(const int* __restrict__ cnt,
                                                    int* __restrict__ row_ptr,
                                                    int* __restrict__ wr_ptr) {
    __shared__ int s[1024];
    __shared__ int carry;
    if (threadIdx.x == 0) carry = 0;
    __syncthreads();
    for (int base = 0; base < NN; base += 1024) {
        int i = base + (int)threadIdx.x;
        int v = (i < NN) ? cnt[i] : 0;
        s[threadIdx.x] = v;
        __syncthreads();
        for (int off = 1; off < 1024; off <<= 1) {
            int t = (threadIdx.x >= (unsigned)off) ? s[threadIdx.x - off] : 0;
            __syncthreads();
            s[threadIdx.x] += t;
            __syncthreads();
        }
        int excl = s[threadIdx.x] - v + carry;
        if (i < NN) { row_ptr[i] = excl; wr_ptr[i] = excl; }
        __syncthreads();
        if (threadIdx.x == 0) carry += s[1023];
        __syncthreads();
    }
    if (threadIdx.x == 0) { row_ptr[NN] = carry; wr_ptr[NN] = carry; }
}

__global__ void scatter_kernel(const int* __restrict__ src, const int* __restrict__ dst,
                               int* __restrict__ wr_ptr, int* __restrict__ srcs) {
    int e = blockIdx.x * blockDim.x + threadIdx.x;
    if (e < NE) {
        int pos = atomicAdd(&wr_ptr[dst[e]], 1);
        srcs[pos] = src[e];
    }
}

// ---------------- h = x @ W, fused alpha_s/alpha_d head reductions ----------
// Block = 128 threads (thread j owns output column j), ROWS rows per block.
// a_src[l] is [H][F] which flattens to exactly column index j -> per-head
// reduction is a width-32 shuffle reduce.
constexpr int ROWS = 8;
__global__ __launch_bounds__(128) void gemm_alpha_kernel(
    const float* __restrict__ x, const float* __restrict__ W,
    const float* __restrict__ a_src, const float* __restrict__ a_dst,
    float* __restrict__ h, float* __restrict__ alpha_s, float* __restrict__ alpha_d)
{
    __shared__ float xs[ROWS][D];
    const int j = threadIdx.x;
    const int row0 = blockIdx.x * ROWS;
    #pragma unroll
    for (int r = 0; r < ROWS; ++r) {
        int n = row0 + r;
        xs[r][j] = (n < NN) ? x[(size_t)n * D + j] : 0.f;
    }
    __syncthreads();
    float acc[ROWS];
    #pragma unroll
    for (int r = 0; r < ROWS; ++r) acc[r] = 0.f;
    for (int k = 0; k < D; ++k) {
        float w = W[k * D + j];
        #pragma unroll
        for (int r = 0; r < ROWS; ++r) acc[r] = fmaf(xs[r][k], w, acc[r]);
    }
    const float as = a_src[j], ad = a_dst[j];
    #pragma unroll
    for (int r = 0; r < ROWS; ++r) {
        int n = row0 + r;
        if (n < NN) h[(size_t)n * D + j] = acc[r];
        float vs = acc[r] * as;
        float vd = acc[r] * ad;
        #pragma unroll
        for (int off = 16; off; off >>= 1) {
            vs += __shfl_xor(vs, off, 32);
            vd += __shfl_xor(vd, off, 32);
        }
        if ((j & 31) == 0 && n < NN) {
            alpha_s[n * NH + (j >> 5)] = vs;
            alpha_d[n * NH + (j >> 5)] = vd;
        }
    }
}

// ---------------- per-dst-node gather + softmax + aggregate + epilogue ------
// One 64-lane wave per node. Lane owns columns (lane, lane+64).
// Per 64-edge chunk: lane computes the 4 head weights w=exp(lrelu(...)) for
// its edge; inner loop broadcasts (src, w[0..3]) via shuffles; accumulate
// unnormalized; divide by denom at the end (normalization commutes with sum).
__global__ __launch_bounds__(256) void gather_kernel(
    const float* __restrict__ h, const float* __restrict__ alpha_s,
    const float* __restrict__ alpha_d, const int* __restrict__ row_ptr,
    const int* __restrict__ srcs, const float* __restrict__ x_in,
    const float* __restrict__ bias, float* __restrict__ out, int apply_act)
{
    const int wave = threadIdx.x >> 6;
    const int lane = threadIdx.x & 63;
    const int n = blockIdx.x * 4 + wave;
    if (n >= NN) return;

    const int start = row_ptr[n];
    const int end   = row_ptr[n + 1];
    const float4 ad4 = *(const float4*)&alpha_d[n * NH];

    float acc0 = 0.f, acc1 = 0.f;
    float ds0 = 0.f, ds1 = 0.f, ds2 = 0.f, ds3 = 0.f;
    const bool hi = (lane >= 32);   // head within (0,1) for col0, (2,3) for col1

    for (int base = start; base < end; base += 64) {
        int my = base + lane;
        int msrc = 0;
        float w0 = 0.f, w1 = 0.f, w2 = 0.f, w3 = 0.f;
        if (my < end) {
            msrc = srcs[my];
            const float4 as4 = *(const float4*)&alpha_s[msrc * NH];
            float e0 = as4.x + ad4.x; e0 = (e0 > 0.f) ? e0 : 0.2f * e0;
            float e1 = as4.y + ad4.y; e1 = (e1 > 0.f) ? e1 : 0.2f * e1;
            float e2 = as4.z + ad4.z; e2 = (e2 > 0.f) ? e2 : 0.2f * e2;
            float e3 = as4.w + ad4.w; e3 = (e3 > 0.f) ? e3 : 0.2f * e3;
            w0 = __expf(e0); w1 = __expf(e1); w2 = __expf(e2); w3 = __expf(e3);
            ds0 += w0; ds1 += w1; ds2 += w2; ds3 += w3;
        }
        const int cnt = min(64, end - base);
        for (int m = 0; m < cnt; ++m) {
            int s = __shfl(msrc, m);
            float b0 = __shfl(w0, m), b1 = __shfl(w1, m);
            float b2 = __shfl(w2, m), b3 = __shfl(w3, m);
            float wA = hi ? b1 : b0;
            float wB = hi ? b3 : b2;
            const float* hr = h + (size_t)s * D;
            acc0 = fmaf(wA, hr[lane], acc0);
            acc1 = fmaf(wB, hr[64 + lane], acc1);
        }
    }
    // reduce denominators across the wave
    #pragma unroll
    for (int off = 32; off; off >>= 1) {
        ds0 += __shfl_xor(ds0, off);
        ds1 += __shfl_xor(ds1, off);
        ds2 += __shfl_xor(ds2, off);
        ds3 += __shfl_xor(ds3, off);
    }
    const float denA = hi ? ds1 : ds0;
    const float denB = hi ? ds3 : ds2;
    float o0 = acc0 / (denA + 1e-16f) + x_in[(size_t)n * D + lane]      + bias[lane];
    float o1 = acc1 / (denB + 1e-16f) + x_in[(size_t)n * D + 64 + lane] + bias[64 + lane];
    if (apply_act) {
        o0 = (o0 > 0.f) ? o0 : expm1f(o0);
        o1 = (o1 > 0.f) ? o1 : expm1f(o1);
    }
    out[(size_t)n * D + lane]      = o0;
    out[(size_t)n * D + 64 + lane] = o1;
}

// ---------------------------------------------------------------------------
extern "C" void kernel_launch(void* const* d_in, const int* in_sizes, int n_in,
                              void* d_out, int out_size, void* d_ws, size_t ws_size,
                              hipStream_t stream) {
    const float* x     = (const float*)d_in[0];
    const int*   ei    = (const int*)d_in[1];
    const float* W     = (const float*)d_in[2];
    const float* a_src = (const float*)d_in[3];
    const float* a_dst = (const float*)d_in[4];
    const float* bias  = (const float*)d_in[5];
    float* outp = (float*)d_out;

    const int* e_src = ei;
    const int* e_dst = ei + NE;

    // workspace layout (bytes)
    char* base = (char*)d_ws;
    float* h       = (float*)(base);                         // NN*D
    float* x1      = (float*)(base + 25600000);              // NN*D
    float* al_s    = (float*)(base + 51200000);              // NN*NH
    float* al_d    = (float*)(base + 52000000);              // NN*NH
    int*   row_ptr = (int*)  (base + 52800000);              // NN+1
    int*   wr_ptr  = (int*)  (base + 52800000 + 200004);     // NN+1
    int*   cnt     = (int*)  (base + 52800000 + 2*200004);   // NN
    int*   srcs    = (int*)  (base + 52800000 + 3*200004);   // NE

    // ---- CSR build (once; graph shared by both layers) ----
    hipMemsetAsync(cnt, 0, NN * sizeof(int), stream);
    hist_kernel<<<(NE + 255) / 256, 256, 0, stream>>>(e_dst, cnt);
    scan_kernel<<<1, 1024, 0, stream>>>(cnt, row_ptr, wr_ptr);
    scatter_kernel<<<(NE + 255) / 256, 256, 0, stream>>>(e_src, e_dst, wr_ptr, srcs);

    const int gemm_blocks   = (NN + ROWS - 1) / ROWS;
    const int gather_blocks = (NN + 3) / 4;

    // ---- layer 0 ----
    gemm_alpha_kernel<<<gemm_blocks, 128, 0, stream>>>(x, W, a_src, a_dst, h, al_s, al_d);
    gather_kernel<<<gather_blocks, 256, 0, stream>>>(h, al_s, al_d, row_ptr, srcs,
                                                     x, bias, x1, 1);
    // ---- layer 1 ----
    gemm_alpha_kernel<<<gemm_blocks, 128, 0, stream>>>(x1, W + D * D, a_src + D,
                                                       a_dst + D, h, al_s, al_d);
    gather_kernel<<<gather_blocks, 256, 0, stream>>>(h, al_s, al_d, row_ptr, srcs,
                                                     x1, bias + D, outp, 0);
}